// Round 2
// baseline (651.495 us; speedup 1.0000x reference)
//
#include <hip/hip_runtime.h>
#include <hip/hip_cooperative_groups.h>
#include <stdint.h>

// GCN 2-layer: out = drop(relu(A_hat * (drop(relu((A_hat*X)*W1+b1)) * W2) + b2))
// v3: cooperative preprocessing mega-kernel (5->1 launches), GEMM double-buffered
//     LDS with counted vmcnt (prefetch across barrier), chunk-XOR LDS swizzle
//     (pre-swizzled global source + swizzled read) to kill 8-way bank conflicts.

#define C_IN 256
#define C_HID 512
#define C_OUT 256

typedef unsigned short ushort_t;
typedef __bf16 bf16x8 __attribute__((ext_vector_type(8)));
typedef float floatx4 __attribute__((ext_vector_type(4)));

typedef __attribute__((address_space(1))) const void g1_void;
typedef __attribute__((address_space(3))) void l3_void;

namespace cg = cooperative_groups;

__device__ __forceinline__ void gll16(const ushort_t* g, ushort_t* l) {
  __builtin_amdgcn_global_load_lds((g1_void*)g, (l3_void*)l, 16, 0, 0);
}

// ---------------- Threefry-2x32 (matches JAX) ----------------
__host__ __device__ __forceinline__ void tf_rounds(unsigned& x0, unsigned& x1,
                                                   unsigned k0, unsigned k1) {
  unsigned k2 = k0 ^ k1 ^ 0x1BD11BDAu;
#define ROT(r) { x0 += x1; x1 = (x1 << r) | (x1 >> (32 - r)); x1 ^= x0; }
  x0 += k0; x1 += k1;
  ROT(13) ROT(15) ROT(26) ROT(6)
  x0 += k1; x1 += k2 + 1u;
  ROT(17) ROT(29) ROT(16) ROT(24)
  x0 += k2; x1 += k0 + 2u;
  ROT(13) ROT(15) ROT(26) ROT(6)
  x0 += k0; x1 += k1 + 3u;
  ROT(17) ROT(29) ROT(16) ROT(24)
  x0 += k1; x1 += k2 + 4u;
  ROT(13) ROT(15) ROT(26) ROT(6)
  x0 += k2; x1 += k0 + 5u;
#undef ROT
}

__device__ __forceinline__ float drop_scale(unsigned j, unsigned k0, unsigned k1) {
  unsigned x0 = 0u, x1 = j;
  tf_rounds(x0, x1, k0, k1);
  unsigned bits = x0 ^ x1;
  float u = __uint_as_float((bits >> 9) | 0x3f800000u) - 1.0f;
  return (u < 0.5f) ? 2.0f : 0.0f;
}

// bf16 helpers (RNE)
__device__ __forceinline__ ushort_t f2bf(float f) {
  unsigned u = __float_as_uint(f);
  unsigned r = (u + 0x7fffu + ((u >> 16) & 1u)) >> 16;
  return (ushort_t)r;
}
__device__ __forceinline__ float bf2f(ushort_t h) {
  return __uint_as_float(((unsigned)h) << 16);
}

// ---------------- cooperative preprocessing mega-kernel ----------------
// P0: zero cnt | detect int64 | weight convert+transpose
// P1: edge convert + degree histogram
// P2: per-block sums   P3: prefix + dinv   P4: CSR scatter
__global__ __launch_bounds__(256) void k_pre(
    const void* __restrict__ raw, unsigned* __restrict__ flag,
    int* __restrict__ cnt, int* __restrict__ bsum,
    int* __restrict__ roff, int* __restrict__ cursor,
    float* __restrict__ dinv, int* __restrict__ eic, int* __restrict__ csr,
    int N, int NB, int E,
    const float* __restrict__ W1, const float* __restrict__ W2,
    ushort_t* __restrict__ wh1, ushort_t* __restrict__ wl1,
    ushort_t* __restrict__ wh2, ushort_t* __restrict__ wl2) {
  cg::grid_group gg = cg::this_grid();
  const int t = threadIdx.x;
  __shared__ int sh[256];
  __shared__ int spre;

  const int S1 = C_IN * C_HID;
  const int WCB = (S1 + C_HID * C_OUT + 255) / 256;
  for (int vb = blockIdx.x; vb < NB + 1 + WCB; vb += gridDim.x) {
    if (vb < NB) {
      int i = vb * 256 + t;
      if (i < N) cnt[i] = 0;
    } else if (vb == NB) {
      unsigned acc = 0;
      const unsigned* r32 = (const unsigned*)raw;
      for (int i = 1 + 2 * t; i < 8192; i += 512) acc |= r32[i];
      ((unsigned*)sh)[t] = acc;
      __syncthreads();
      for (int s = 128; s > 0; s >>= 1) {
        if (t < s) ((unsigned*)sh)[t] |= ((unsigned*)sh)[t + s];
        __syncthreads();
      }
      if (t == 0) *flag = (((unsigned*)sh)[0] == 0u) ? 1u : 0u;  // 1 => int64
    } else {
      int idx = (vb - NB - 1) * 256 + t;
      if (idx < S1 + C_HID * C_OUT) {
        if (idx < S1) {                       // W1 [256][512] -> [512][256]
          int k = idx >> 9, n = idx & 511;
          float v = W1[idx];
          ushort_t h = f2bf(v);
          wh1[(size_t)n * C_IN + k] = h;
          wl1[(size_t)n * C_IN + k] = f2bf(v - bf2f(h));
        } else {                              // W2 [512][256] -> [256][512]
          int li = idx - S1;
          int k = li >> 8, n = li & 255;
          float v = W2[li];
          ushort_t h = f2bf(v);
          wh2[(size_t)n * C_HID + k] = h;
          wl2[(size_t)n * C_HID + k] = f2bf(v - bf2f(h));
        }
      }
    }
    __syncthreads();
  }
  gg.sync();

  // P1: convert + histogram
  for (int vb = blockIdx.x; vb < (2 * E + 255) / 256; vb += gridDim.x) {
    int i = vb * 256 + t;
    if (i < 2 * E) {
      int v;
      if (*flag) v = (int)((const long long*)raw)[i];
      else       v = ((const int*)raw)[i];
      eic[i] = v;
      if (i >= E) atomicAdd(&cnt[v], 1);
    }
  }
  gg.sync();

  // P2: block sums
  for (int vb = blockIdx.x; vb < NB; vb += gridDim.x) {
    int i = vb * 256 + t;
    sh[t] = (i < N) ? cnt[i] : 0;
    __syncthreads();
    for (int s = 128; s > 0; s >>= 1) {
      if (t < s) sh[t] += sh[t + s];
      __syncthreads();
    }
    if (t == 0) bsum[vb] = sh[0];
    __syncthreads();
  }
  gg.sync();

  // P3: prefix (wave0 reduces prior block sums) + emit roff/cursor/dinv
  for (int vb = blockIdx.x; vb < NB; vb += gridDim.x) {
    if (t < 64) {
      int v = (t < vb) ? bsum[t] : 0;
      for (int s = 32; s > 0; s >>= 1) v += __shfl_down(v, s);
      if (t == 0) spre = v;
    }
    int i = vb * 256 + t;
    int v = (i < N) ? cnt[i] : 0;
    sh[t] = v;
    __syncthreads();
    for (int s = 1; s < 256; s <<= 1) {
      int tv = (t >= s) ? sh[t - s] : 0;
      __syncthreads();
      sh[t] += tv;
      __syncthreads();
    }
    if (i < N) {
      int excl = spre + sh[t] - v;
      roff[i] = excl;
      cursor[i] = excl;
      dinv[i] = rsqrtf((float)(v + 1));  // +1 self-loop
    }
    if (vb == 0 && t == 0) roff[N] = E;
    __syncthreads();
  }
  gg.sync();

  // P4: scatter
  for (int vb = blockIdx.x; vb < (E + 255) / 256; vb += gridDim.x) {
    int e = vb * 256 + t;
    if (e < E) {
      int s = eic[e], d = eic[E + e];
      int slot = atomicAdd(&cursor[d], 1);
      csr[slot] = s;
    }
  }
}

// ---------------- gather: 4 nodes/block, 64 lanes x float4, unroll-8 --------
template <int EPI, int PRE>
__global__ __launch_bounds__(256) void k_gather4(const int* __restrict__ roff,
                                                 const int* __restrict__ csr,
                                                 const float* __restrict__ dinv,
                                                 const float* __restrict__ x,
                                                 const float* __restrict__ bias,
                                                 void* __restrict__ o1,
                                                 void* __restrict__ o2,
                                                 unsigned dk0, unsigned dk1) {
  int g = threadIdx.x >> 6;
  int tg = threadIdx.x & 63;
  int node = blockIdx.x * 4 + g;
  float dd = dinv[node];
  const float4* xr = (const float4*)x;
  float4 v = xr[(size_t)node * 64 + tg];
  float4 acc;
  if (PRE) acc = v;
  else acc = make_float4(dd * v.x, dd * v.y, dd * v.z, dd * v.w);
  int p = roff[node], end = roff[node + 1];
  for (; p + 8 <= end; p += 8) {
    int s[8];
#pragma unroll
    for (int q = 0; q < 8; ++q) s[q] = csr[p + q];
    float4 r[8];
#pragma unroll
    for (int q = 0; q < 8; ++q) r[q] = xr[(size_t)s[q] * 64 + tg];
    if (PRE) {
#pragma unroll
      for (int q = 0; q < 8; ++q) {
        acc.x += r[q].x; acc.y += r[q].y; acc.z += r[q].z; acc.w += r[q].w;
      }
    } else {
      float w[8];
#pragma unroll
      for (int q = 0; q < 8; ++q) w[q] = dinv[s[q]];
#pragma unroll
      for (int q = 0; q < 8; ++q) {
        acc.x += w[q] * r[q].x; acc.y += w[q] * r[q].y;
        acc.z += w[q] * r[q].z; acc.w += w[q] * r[q].w;
      }
    }
  }
  for (; p + 4 <= end; p += 4) {
    int s0 = csr[p], s1 = csr[p + 1], s2 = csr[p + 2], s3 = csr[p + 3];
    float4 a = xr[(size_t)s0 * 64 + tg];
    float4 b = xr[(size_t)s1 * 64 + tg];
    float4 c = xr[(size_t)s2 * 64 + tg];
    float4 d = xr[(size_t)s3 * 64 + tg];
    if (PRE) {
      acc.x += a.x + b.x + c.x + d.x;
      acc.y += a.y + b.y + c.y + d.y;
      acc.z += a.z + b.z + c.z + d.z;
      acc.w += a.w + b.w + c.w + d.w;
    } else {
      float w0 = dinv[s0], w1 = dinv[s1], w2 = dinv[s2], w3 = dinv[s3];
      acc.x += w0 * a.x + w1 * b.x + w2 * c.x + w3 * d.x;
      acc.y += w0 * a.y + w1 * b.y + w2 * c.y + w3 * d.y;
      acc.z += w0 * a.z + w1 * b.z + w2 * c.z + w3 * d.z;
      acc.w += w0 * a.w + w1 * b.w + w2 * c.w + w3 * d.w;
    }
  }
  for (; p < end; ++p) {
    int s0 = csr[p];
    float4 a = xr[(size_t)s0 * 64 + tg];
    if (PRE) {
      acc.x += a.x; acc.y += a.y; acc.z += a.z; acc.w += a.w;
    } else {
      float w0 = dinv[s0];
      acc.x += w0 * a.x; acc.y += w0 * a.y; acc.z += w0 * a.z; acc.w += w0 * a.w;
    }
  }
  acc.x *= dd; acc.y *= dd; acc.z *= dd; acc.w *= dd;
  if (EPI) {
    float4 bb = ((const float4*)bias)[tg];
    acc.x = fmaxf(acc.x + bb.x, 0.0f);
    acc.y = fmaxf(acc.y + bb.y, 0.0f);
    acc.z = fmaxf(acc.z + bb.z, 0.0f);
    acc.w = fmaxf(acc.w + bb.w, 0.0f);
    unsigned jb = (unsigned)node * 256u + (unsigned)tg * 4u;
    acc.x *= drop_scale(jb + 0u, dk0, dk1);
    acc.y *= drop_scale(jb + 1u, dk0, dk1);
    acc.z *= drop_scale(jb + 2u, dk0, dk1);
    acc.w *= drop_scale(jb + 3u, dk0, dk1);
    ((float4*)o1)[(size_t)node * 64 + tg] = acc;
  } else {
    ushort_t h0 = f2bf(acc.x), h1 = f2bf(acc.y), h2 = f2bf(acc.z), h3 = f2bf(acc.w);
    ushort4 hv = make_ushort4(h0, h1, h2, h3);
    ushort4 lv = make_ushort4(f2bf(acc.x - bf2f(h0)), f2bf(acc.y - bf2f(h1)),
                              f2bf(acc.z - bf2f(h2)), f2bf(acc.w - bf2f(h3)));
    ((ushort4*)o1)[(size_t)node * 64 + tg] = hv;
    ((ushort4*)o2)[(size_t)node * 64 + tg] = lv;
  }
}

// ---------------- bf16x3 MFMA GEMM: 64x128 tile, dbuf gll16 + counted vmcnt -
// LDS chunk-XOR swizzle: global source pre-swizzled (skc), reads XOR chunk (qx8).
template <int EPI>
__global__ __launch_bounds__(256) void k_gemm3(
    const ushort_t* __restrict__ Ahi, const ushort_t* __restrict__ Alo,
    const ushort_t* __restrict__ Bhi, const ushort_t* __restrict__ Blo,
    const float* __restrict__ bias, const float* __restrict__ dscale,
    ushort_t* __restrict__ Chi, ushort_t* __restrict__ Clo,
    float* __restrict__ Cf,
    int M, int N, int K, unsigned dk0, unsigned dk1) {
  __shared__ ushort_t sAh[2][64 * 32], sAl[2][64 * 32];
  __shared__ ushort_t sBh[2][128 * 32], sBl[2][128 * 32];
  const int t = threadIdx.x;
  const int lane = t & 63, wave = t >> 6;
  const int wm = wave & 1, wn = wave >> 1;
  const int quad = lane >> 4, l16 = lane & 15;
  const int row0 = blockIdx.y * 64, col0 = blockIdx.x * 128;
  const int srow = t >> 2;
  const int skc = (((t & 3) ^ ((t >> 3) & 3)) * 8);   // swizzled source chunk
  const int qx8 = (quad ^ ((l16 >> 1) & 3)) * 8;      // swizzled read chunk

  floatx4 acc[2][4] = {};

  const int ra  = min(row0 + srow, M - 1);
  const int rb0 = col0 + srow;
  const int rb1 = col0 + 64 + srow;

  const ushort_t* gAh = Ahi + (size_t)ra * K + skc;
  const ushort_t* gAl = Alo + (size_t)ra * K + skc;
  const ushort_t* gB0h = Bhi + (size_t)rb0 * K + skc;
  const ushort_t* gB1h = Bhi + (size_t)rb1 * K + skc;
  const ushort_t* gB0l = Blo + (size_t)rb0 * K + skc;
  const ushort_t* gB1l = Blo + (size_t)rb1 * K + skc;

#define STAGE(c, kt) {                                  \
    gll16(gAh + (kt), &sAh[c][wave * 512]);             \
    gll16(gAl + (kt), &sAl[c][wave * 512]);             \
    gll16(gB0h + (kt), &sBh[c][wave * 512]);            \
    gll16(gB1h + (kt), &sBh[c][2048 + wave * 512]);     \
    gll16(gB0l + (kt), &sBl[c][wave * 512]);            \
    gll16(gB1l + (kt), &sBl[c][2048 + wave * 512]); }

  const int nk = K >> 5;
  STAGE(0, 0)
  for (int it = 0; it < nk; ++it) {
    const int c = it & 1;
    if (it + 1 < nk) {
      STAGE(c ^ 1, (it + 1) * 32)
      asm volatile("s_waitcnt vmcnt(6)\n\ts_barrier" ::: "memory");
    } else {
      asm volatile("s_waitcnt vmcnt(0)\n\ts_barrier" ::: "memory");
    }

    bf16x8 ah[2], al[2], bh[4], bl[4];
#pragma unroll
    for (int i = 0; i < 2; ++i) {
      int off = (wm * 32 + i * 16 + l16) * 32 + qx8;
      ah[i] = *(const bf16x8*)&sAh[c][off];
      al[i] = *(const bf16x8*)&sAl[c][off];
    }
#pragma unroll
    for (int j = 0; j < 4; ++j) {
      int off = (wn * 64 + j * 16 + l16) * 32 + qx8;
      bh[j] = *(const bf16x8*)&sBh[c][off];
      bl[j] = *(const bf16x8*)&sBl[c][off];
    }
#pragma unroll
    for (int i = 0; i < 2; ++i)
#pragma unroll
      for (int j = 0; j < 4; ++j) {
        acc[i][j] = __builtin_amdgcn_mfma_f32_16x16x32_bf16(ah[i], bh[j], acc[i][j], 0, 0, 0);
        acc[i][j] = __builtin_amdgcn_mfma_f32_16x16x32_bf16(ah[i], bl[j], acc[i][j], 0, 0, 0);
        acc[i][j] = __builtin_amdgcn_mfma_f32_16x16x32_bf16(al[i], bh[j], acc[i][j], 0, 0, 0);
      }
    asm volatile("s_barrier" ::: "memory");  // reads done before next stage overwrites
  }
#undef STAGE

#pragma unroll
  for (int i = 0; i < 2; ++i) {
#pragma unroll
    for (int j = 0; j < 4; ++j) {
      int gc = col0 + wn * 64 + j * 16 + l16;
#pragma unroll
      for (int reg = 0; reg < 4; ++reg) {
        int gr = row0 + wm * 32 + i * 16 + quad * 4 + reg;
        if (gr >= M) continue;
        float v = acc[i][j][reg];
        size_t o = (size_t)gr * N + gc;
        if (EPI) {
          v += bias[gc];
          v = fmaxf(v, 0.0f);
          v *= drop_scale((unsigned)gr * (unsigned)N + (unsigned)gc, dk0, dk1);
          ushort_t h = f2bf(v);
          Chi[o] = h;
          Clo[o] = f2bf(v - bf2f(h));
        } else {
          Cf[o] = v * dscale[gr];  // row-prescale by dinv for gather2
        }
      }
    }
  }
}

extern "C" void kernel_launch(void* const* d_in, const int* in_sizes, int n_in,
                              void* d_out, int out_size, void* d_ws, size_t ws_size,
                              hipStream_t stream) {
  const float* x  = (const float*)d_in[0];
  const void*  ei = d_in[1];
  const float* W1 = (const float*)d_in[2];
  const float* b1 = (const float*)d_in[3];
  const float* W2 = (const float*)d_in[4];
  const float* b2 = (const float*)d_in[5];
  float* out = (float*)d_out;

  const int N = in_sizes[0] / C_IN;   // 10000
  const int E = in_sizes[1] / 2;      // 160000
  const int NB = (N + 255) / 256;     // 40 scan blocks

  // foldlike split(key(42)): dk_i = threefry((0,42), (0, i))
  unsigned a0 = 0u, a1 = 0u, b0 = 0u, b1k = 1u;
  tf_rounds(a0, a1, 0u, 42u);   // dk1
  tf_rounds(b0, b1k, 0u, 42u);  // dk2

  // workspace layout
  uintptr_t base = (uintptr_t)d_ws;
  unsigned*  flag   = (unsigned*)base;
  int*       bsum   = (int*)(base + 4096);
  int*       cnt    = (int*)(base + 16 * 1024);
  int*       roff   = (int*)(base + 64 * 1024);
  int*       cursor = (int*)(base + 128 * 1024);
  float*     dinv   = (float*)(base + 192 * 1024);
  int*       eic    = (int*)(base + 256 * 1024);
  int*       csr    = (int*)(base + 2u * 1024 * 1024);
  ushort_t*  Ahi    = (ushort_t*)(base + 4u  * 1024 * 1024);
  ushort_t*  Alo    = (ushort_t*)(base + 10u * 1024 * 1024);
  ushort_t*  H1hi   = (ushort_t*)(base + 16u * 1024 * 1024);
  ushort_t*  H1lo   = (ushort_t*)(base + 27u * 1024 * 1024);
  float*     hw2    = (float*)(base + 38u * 1024 * 1024);
  ushort_t*  W1thi  = (ushort_t*)(base + 49u * 1024 * 1024);
  ushort_t*  W1tlo  = (ushort_t*)(base + 49u * 1024 * 1024 + 512 * 1024);
  ushort_t*  W2thi  = (ushort_t*)(base + 50u * 1024 * 1024);
  ushort_t*  W2tlo  = (ushort_t*)(base + 50u * 1024 * 1024 + 512 * 1024);

  dim3 b256(256);

  // 1. cooperative preprocessing (zero|detect|wconv -> convert -> scan -> scatter)
  int Nv = N, NBv = NB, Ev = E;
  const void* rawp = ei;
  void* args[] = {
      (void*)&rawp, (void*)&flag, (void*)&cnt, (void*)&bsum, (void*)&roff,
      (void*)&cursor, (void*)&dinv, (void*)&eic, (void*)&csr,
      (void*)&Nv, (void*)&NBv, (void*)&Ev,
      (void*)&W1, (void*)&W2,
      (void*)&W1thi, (void*)&W1tlo, (void*)&W2thi, (void*)&W2tlo};
  hipLaunchCooperativeKernel((const void*)k_pre, dim3(1024), b256, args, 0, stream);

  // 2. layer 1 aggregate (gather) -> bf16 split A
  k_gather4<0, 0><<<dim3(N / 4), b256, 0, stream>>>(roff, csr, dinv, x, nullptr,
                                                    Ahi, Alo, 0u, 0u);
  // 3. h1 = drop(relu(agg @ W1 + b1)) -> bf16 split   [grid 4 x 157]
  k_gemm3<1><<<dim3(C_HID / 128, (N + 63) / 64), b256, 0, stream>>>(
      Ahi, Alo, W1thi, W1tlo, b1, nullptr, H1hi, H1lo, nullptr,
      N, C_HID, C_IN, a0, a1);
  // 4. hw2' = dinv * (h1 @ W2)  (fp32, row-prescaled)  [grid 2 x 157]
  k_gemm3<0><<<dim3(C_OUT / 128, (N + 63) / 64), b256, 0, stream>>>(
      H1hi, H1lo, W2thi, W2tlo, nullptr, dinv, nullptr, nullptr, hw2,
      N, C_OUT, C_HID, 0u, 0u);
  // 5. out = drop(relu(dd * (sum hw2'[nbrs] + hw2'[self]) + b2))
  k_gather4<1, 1><<<dim3(N / 4), b256, 0, stream>>>(roff, csr, dinv, hw2, b2,
                                                    out, nullptr, b0, b1k);
}

// Round 3
// 198.244 us; speedup vs baseline: 3.2863x; 3.2863x over previous
//
#include <hip/hip_runtime.h>
#include <stdint.h>

// GCN 2-layer: out = drop(relu(A_hat * (drop(relu((A_hat*X)*W1+b1)) * W2) + b2))
// v4: v2 preprocessing (5 small launches; cooperative grid.sync measured 475us - reverted)
//     + v3 GEMM (dbuf global_load_lds, counted vmcnt(6), chunk-XOR LDS swizzle).

#define C_IN 256
#define C_HID 512
#define C_OUT 256

typedef unsigned short ushort_t;
typedef __bf16 bf16x8 __attribute__((ext_vector_type(8)));
typedef float floatx4 __attribute__((ext_vector_type(4)));

typedef __attribute__((address_space(1))) const void g1_void;
typedef __attribute__((address_space(3))) void l3_void;

__device__ __forceinline__ void gll16(const ushort_t* g, ushort_t* l) {
  __builtin_amdgcn_global_load_lds((g1_void*)g, (l3_void*)l, 16, 0, 0);
}

// ---------------- Threefry-2x32 (matches JAX) ----------------
__host__ __device__ __forceinline__ void tf_rounds(unsigned& x0, unsigned& x1,
                                                   unsigned k0, unsigned k1) {
  unsigned k2 = k0 ^ k1 ^ 0x1BD11BDAu;
#define ROT(r) { x0 += x1; x1 = (x1 << r) | (x1 >> (32 - r)); x1 ^= x0; }
  x0 += k0; x1 += k1;
  ROT(13) ROT(15) ROT(26) ROT(6)
  x0 += k1; x1 += k2 + 1u;
  ROT(17) ROT(29) ROT(16) ROT(24)
  x0 += k2; x1 += k0 + 2u;
  ROT(13) ROT(15) ROT(26) ROT(6)
  x0 += k0; x1 += k1 + 3u;
  ROT(17) ROT(29) ROT(16) ROT(24)
  x0 += k1; x1 += k2 + 4u;
  ROT(13) ROT(15) ROT(26) ROT(6)
  x0 += k2; x1 += k0 + 5u;
#undef ROT
}

__device__ __forceinline__ float drop_scale(unsigned j, unsigned k0, unsigned k1) {
  unsigned x0 = 0u, x1 = j;
  tf_rounds(x0, x1, k0, k1);
  unsigned bits = x0 ^ x1;
  float u = __uint_as_float((bits >> 9) | 0x3f800000u) - 1.0f;
  return (u < 0.5f) ? 2.0f : 0.0f;
}

// bf16 helpers (RNE)
__device__ __forceinline__ ushort_t f2bf(float f) {
  unsigned u = __float_as_uint(f);
  unsigned r = (u + 0x7fffu + ((u >> 16) & 1u)) >> 16;
  return (ushort_t)r;
}
__device__ __forceinline__ float bf2f(ushort_t h) {
  return __uint_as_float(((unsigned)h) << 16);
}

// ---------------- fused setup: zero cnt | detect dtype | weight convert ----
// blocks [0,NB): zero cnt ; block NB: detect ; blocks (NB, NB+1024]: wconv
__global__ __launch_bounds__(256) void k_setup(const unsigned* __restrict__ raw,
                                               unsigned* __restrict__ flag,
                                               int* __restrict__ cnt, int N, int NB,
                                               const float* __restrict__ W1,
                                               const float* __restrict__ W2,
                                               ushort_t* __restrict__ h1,
                                               ushort_t* __restrict__ l1,
                                               ushort_t* __restrict__ h2,
                                               ushort_t* __restrict__ l2) {
  int b = blockIdx.x, t = threadIdx.x;
  if (b < NB) {
    int i = b * 256 + t;
    if (i < N) cnt[i] = 0;
    return;
  }
  if (b == NB) {
    __shared__ unsigned sh[256];
    unsigned acc = 0;
    for (int i = 1 + 2 * t; i < 8192; i += 512) acc |= raw[i];
    sh[t] = acc;
    __syncthreads();
    for (int s = 128; s > 0; s >>= 1) {
      if (t < s) sh[t] |= sh[t + s];
      __syncthreads();
    }
    if (t == 0) *flag = (sh[0] == 0u) ? 1u : 0u;  // 1 => int64
    return;
  }
  int idx = (b - NB - 1) * 256 + t;
  const int S1 = C_IN * C_HID;
  if (idx >= S1 + C_HID * C_OUT) return;
  const float* W; ushort_t *hi, *lo; int K, Nn, li;
  if (idx < S1) { W = W1; hi = h1; lo = l1; K = C_IN; Nn = C_HID; li = idx; }
  else { W = W2; hi = h2; lo = l2; K = C_HID; Nn = C_OUT; li = idx - S1; }
  int k = li / Nn, n = li - k * Nn;
  float v = W[li];
  ushort_t h = f2bf(v);
  hi[(size_t)n * K + k] = h;
  lo[(size_t)n * K + k] = f2bf(v - bf2f(h));
}

// convert + fused dst-degree histogram (cnt must be pre-zeroed)
__global__ __launch_bounds__(256) void k_convert(const void* __restrict__ raw,
                                                 const unsigned* __restrict__ flag,
                                                 int* __restrict__ eic,
                                                 int* __restrict__ cnt,
                                                 int E) {
  int i = blockIdx.x * 256 + threadIdx.x;
  if (i >= 2 * E) return;
  int v;
  if (*flag) v = (int)((const long long*)raw)[i];
  else       v = ((const int*)raw)[i];
  eic[i] = v;
  if (i >= E) atomicAdd(&cnt[v], 1);  // dst half -> in-degree
}

// ---------------- scan: A (block sums), C (per-block prefix of bsum + emit) -
__global__ __launch_bounds__(256) void k_scan_a(const int* __restrict__ cnt,
                                                int* __restrict__ bsum, int n) {
  __shared__ int sh[256];
  int i = blockIdx.x * 256 + threadIdx.x;
  sh[threadIdx.x] = (i < n) ? cnt[i] : 0;
  __syncthreads();
  for (int s = 128; s > 0; s >>= 1) {
    if ((int)threadIdx.x < s) sh[threadIdx.x] += sh[threadIdx.x + s];
    __syncthreads();
  }
  if (threadIdx.x == 0) bsum[blockIdx.x] = sh[0];
}

// phase C: wave0 reduces bsum[0..blockIdx) itself; in-block scan + fused dinv.
__global__ __launch_bounds__(256) void k_scan_c(const int* __restrict__ cnt,
                                                const int* __restrict__ bsum,
                                                int* __restrict__ roff,
                                                int* __restrict__ cursor,
                                                float* __restrict__ dinv,
                                                int n, int NB, int E) {
  __shared__ int sh[256];
  __shared__ int spre;
  int t = threadIdx.x;
  if (t < 64) {
    int v = (t < (int)blockIdx.x && t < NB) ? bsum[t] : 0;
    for (int s = 32; s > 0; s >>= 1) v += __shfl_down(v, s);
    if (t == 0) spre = v;
  }
  int i = blockIdx.x * 256 + t;
  int v = (i < n) ? cnt[i] : 0;
  sh[t] = v;
  __syncthreads();
  for (int s = 1; s < 256; s <<= 1) {
    int tv = (t >= s) ? sh[t - s] : 0;
    __syncthreads();
    sh[t] += tv;
    __syncthreads();
  }
  if (i < n) {
    int excl = spre + sh[t] - v;
    roff[i] = excl;
    cursor[i] = excl;
    dinv[i] = rsqrtf((float)(v + 1));  // +1 self-loop
  }
  if (blockIdx.x == 0 && t == 0) roff[n] = E;
}

__global__ __launch_bounds__(256) void k_scatter(const int* __restrict__ eic,
                                                 int* __restrict__ cursor,
                                                 int* __restrict__ csr, int E) {
  int e = blockIdx.x * 256 + threadIdx.x;
  if (e >= E) return;
  int s = eic[e], d = eic[E + e];
  int slot = atomicAdd(&cursor[d], 1);
  csr[slot] = s;
}

// ---------------- gather: 4 nodes/block, 64 lanes x float4, unroll-8 --------
template <int EPI, int PRE>
__global__ __launch_bounds__(256) void k_gather4(const int* __restrict__ roff,
                                                 const int* __restrict__ csr,
                                                 const float* __restrict__ dinv,
                                                 const float* __restrict__ x,
                                                 const float* __restrict__ bias,
                                                 void* __restrict__ o1,
                                                 void* __restrict__ o2,
                                                 unsigned dk0, unsigned dk1) {
  int g = threadIdx.x >> 6;
  int tg = threadIdx.x & 63;
  int node = blockIdx.x * 4 + g;
  float dd = dinv[node];
  const float4* xr = (const float4*)x;
  float4 v = xr[(size_t)node * 64 + tg];
  float4 acc;
  if (PRE) acc = v;
  else acc = make_float4(dd * v.x, dd * v.y, dd * v.z, dd * v.w);
  int p = roff[node], end = roff[node + 1];
  for (; p + 8 <= end; p += 8) {
    int s[8];
#pragma unroll
    for (int q = 0; q < 8; ++q) s[q] = csr[p + q];
    float4 r[8];
#pragma unroll
    for (int q = 0; q < 8; ++q) r[q] = xr[(size_t)s[q] * 64 + tg];
    if (PRE) {
#pragma unroll
      for (int q = 0; q < 8; ++q) {
        acc.x += r[q].x; acc.y += r[q].y; acc.z += r[q].z; acc.w += r[q].w;
      }
    } else {
      float w[8];
#pragma unroll
      for (int q = 0; q < 8; ++q) w[q] = dinv[s[q]];
#pragma unroll
      for (int q = 0; q < 8; ++q) {
        acc.x += w[q] * r[q].x; acc.y += w[q] * r[q].y;
        acc.z += w[q] * r[q].z; acc.w += w[q] * r[q].w;
      }
    }
  }
  for (; p + 4 <= end; p += 4) {
    int s0 = csr[p], s1 = csr[p + 1], s2 = csr[p + 2], s3 = csr[p + 3];
    float4 a = xr[(size_t)s0 * 64 + tg];
    float4 b = xr[(size_t)s1 * 64 + tg];
    float4 c = xr[(size_t)s2 * 64 + tg];
    float4 d = xr[(size_t)s3 * 64 + tg];
    if (PRE) {
      acc.x += a.x + b.x + c.x + d.x;
      acc.y += a.y + b.y + c.y + d.y;
      acc.z += a.z + b.z + c.z + d.z;
      acc.w += a.w + b.w + c.w + d.w;
    } else {
      float w0 = dinv[s0], w1 = dinv[s1], w2 = dinv[s2], w3 = dinv[s3];
      acc.x += w0 * a.x + w1 * b.x + w2 * c.x + w3 * d.x;
      acc.y += w0 * a.y + w1 * b.y + w2 * c.y + w3 * d.y;
      acc.z += w0 * a.z + w1 * b.z + w2 * c.z + w3 * d.z;
      acc.w += w0 * a.w + w1 * b.w + w2 * c.w + w3 * d.w;
    }
  }
  for (; p < end; ++p) {
    int s0 = csr[p];
    float4 a = xr[(size_t)s0 * 64 + tg];
    if (PRE) {
      acc.x += a.x; acc.y += a.y; acc.z += a.z; acc.w += a.w;
    } else {
      float w0 = dinv[s0];
      acc.x += w0 * a.x; acc.y += w0 * a.y; acc.z += w0 * a.z; acc.w += w0 * a.w;
    }
  }
  acc.x *= dd; acc.y *= dd; acc.z *= dd; acc.w *= dd;
  if (EPI) {
    float4 bb = ((const float4*)bias)[tg];
    acc.x = fmaxf(acc.x + bb.x, 0.0f);
    acc.y = fmaxf(acc.y + bb.y, 0.0f);
    acc.z = fmaxf(acc.z + bb.z, 0.0f);
    acc.w = fmaxf(acc.w + bb.w, 0.0f);
    unsigned jb = (unsigned)node * 256u + (unsigned)tg * 4u;
    acc.x *= drop_scale(jb + 0u, dk0, dk1);
    acc.y *= drop_scale(jb + 1u, dk0, dk1);
    acc.z *= drop_scale(jb + 2u, dk0, dk1);
    acc.w *= drop_scale(jb + 3u, dk0, dk1);
    ((float4*)o1)[(size_t)node * 64 + tg] = acc;
  } else {
    ushort_t h0 = f2bf(acc.x), h1 = f2bf(acc.y), h2 = f2bf(acc.z), h3 = f2bf(acc.w);
    ushort4 hv = make_ushort4(h0, h1, h2, h3);
    ushort4 lv = make_ushort4(f2bf(acc.x - bf2f(h0)), f2bf(acc.y - bf2f(h1)),
                              f2bf(acc.z - bf2f(h2)), f2bf(acc.w - bf2f(h3)));
    ((ushort4*)o1)[(size_t)node * 64 + tg] = hv;
    ((ushort4*)o2)[(size_t)node * 64 + tg] = lv;
  }
}

// ---------------- bf16x3 MFMA GEMM: 64x128 tile, dbuf gll16 + counted vmcnt -
// LDS chunk-XOR swizzle: global source pre-swizzled (skc), reads XOR chunk (qx8).
template <int EPI>
__global__ __launch_bounds__(256) void k_gemm3(
    const ushort_t* __restrict__ Ahi, const ushort_t* __restrict__ Alo,
    const ushort_t* __restrict__ Bhi, const ushort_t* __restrict__ Blo,
    const float* __restrict__ bias, const float* __restrict__ dscale,
    ushort_t* __restrict__ Chi, ushort_t* __restrict__ Clo,
    float* __restrict__ Cf,
    int M, int N, int K, unsigned dk0, unsigned dk1) {
  __shared__ ushort_t sAh[2][64 * 32], sAl[2][64 * 32];
  __shared__ ushort_t sBh[2][128 * 32], sBl[2][128 * 32];
  const int t = threadIdx.x;
  const int lane = t & 63, wave = t >> 6;
  const int wm = wave & 1, wn = wave >> 1;
  const int quad = lane >> 4, l16 = lane & 15;
  const int row0 = blockIdx.y * 64, col0 = blockIdx.x * 128;
  const int srow = t >> 2;
  const int skc = (((t & 3) ^ ((t >> 3) & 3)) * 8);   // swizzled source chunk
  const int qx8 = (quad ^ ((l16 >> 1) & 3)) * 8;      // swizzled read chunk

  floatx4 acc[2][4] = {};

  const int ra  = min(row0 + srow, M - 1);
  const int rb0 = col0 + srow;
  const int rb1 = col0 + 64 + srow;

  const ushort_t* gAh = Ahi + (size_t)ra * K + skc;
  const ushort_t* gAl = Alo + (size_t)ra * K + skc;
  const ushort_t* gB0h = Bhi + (size_t)rb0 * K + skc;
  const ushort_t* gB1h = Bhi + (size_t)rb1 * K + skc;
  const ushort_t* gB0l = Blo + (size_t)rb0 * K + skc;
  const ushort_t* gB1l = Blo + (size_t)rb1 * K + skc;

#define STAGE(c, kt) {                                  \
    gll16(gAh + (kt), &sAh[c][wave * 512]);             \
    gll16(gAl + (kt), &sAl[c][wave * 512]);             \
    gll16(gB0h + (kt), &sBh[c][wave * 512]);            \
    gll16(gB1h + (kt), &sBh[c][2048 + wave * 512]);     \
    gll16(gB0l + (kt), &sBl[c][wave * 512]);            \
    gll16(gB1l + (kt), &sBl[c][2048 + wave * 512]); }

  const int nk = K >> 5;
  STAGE(0, 0)
  for (int it = 0; it < nk; ++it) {
    const int c = it & 1;
    if (it + 1 < nk) {
      STAGE(c ^ 1, (it + 1) * 32)
      asm volatile("s_waitcnt vmcnt(6)\n\ts_barrier" ::: "memory");
    } else {
      asm volatile("s_waitcnt vmcnt(0)\n\ts_barrier" ::: "memory");
    }

    bf16x8 ah[2], al[2], bh[4], bl[4];
#pragma unroll
    for (int i = 0; i < 2; ++i) {
      int off = (wm * 32 + i * 16 + l16) * 32 + qx8;
      ah[i] = *(const bf16x8*)&sAh[c][off];
      al[i] = *(const bf16x8*)&sAl[c][off];
    }
#pragma unroll
    for (int j = 0; j < 4; ++j) {
      int off = (wn * 64 + j * 16 + l16) * 32 + qx8;
      bh[j] = *(const bf16x8*)&sBh[c][off];
      bl[j] = *(const bf16x8*)&sBl[c][off];
    }
#pragma unroll
    for (int i = 0; i < 2; ++i)
#pragma unroll
      for (int j = 0; j < 4; ++j) {
        acc[i][j] = __builtin_amdgcn_mfma_f32_16x16x32_bf16(ah[i], bh[j], acc[i][j], 0, 0, 0);
        acc[i][j] = __builtin_amdgcn_mfma_f32_16x16x32_bf16(ah[i], bl[j], acc[i][j], 0, 0, 0);
        acc[i][j] = __builtin_amdgcn_mfma_f32_16x16x32_bf16(al[i], bh[j], acc[i][j], 0, 0, 0);
      }
    asm volatile("s_barrier" ::: "memory");  // reads done before next stage overwrites
  }
#undef STAGE

#pragma unroll
  for (int i = 0; i < 2; ++i) {
#pragma unroll
    for (int j = 0; j < 4; ++j) {
      int gc = col0 + wn * 64 + j * 16 + l16;
#pragma unroll
      for (int reg = 0; reg < 4; ++reg) {
        int gr = row0 + wm * 32 + i * 16 + quad * 4 + reg;
        if (gr >= M) continue;
        float v = acc[i][j][reg];
        size_t o = (size_t)gr * N + gc;
        if (EPI) {
          v += bias[gc];
          v = fmaxf(v, 0.0f);
          v *= drop_scale((unsigned)gr * (unsigned)N + (unsigned)gc, dk0, dk1);
          ushort_t h = f2bf(v);
          Chi[o] = h;
          Clo[o] = f2bf(v - bf2f(h));
        } else {
          Cf[o] = v * dscale[gr];  // row-prescale by dinv for gather2
        }
      }
    }
  }
}

extern "C" void kernel_launch(void* const* d_in, const int* in_sizes, int n_in,
                              void* d_out, int out_size, void* d_ws, size_t ws_size,
                              hipStream_t stream) {
  const float* x  = (const float*)d_in[0];
  const void*  ei = d_in[1];
  const float* W1 = (const float*)d_in[2];
  const float* b1 = (const float*)d_in[3];
  const float* W2 = (const float*)d_in[4];
  const float* b2 = (const float*)d_in[5];
  float* out = (float*)d_out;

  const int N = in_sizes[0] / C_IN;   // 10000
  const int E = in_sizes[1] / 2;      // 160000
  const int NB = (N + 255) / 256;     // 40 scan blocks

  // foldlike split(key(42)): dk_i = threefry((0,42), (0, i))
  unsigned a0 = 0u, a1 = 0u, b0 = 0u, b1k = 1u;
  tf_rounds(a0, a1, 0u, 42u);   // dk1
  tf_rounds(b0, b1k, 0u, 42u);  // dk2

  // workspace layout
  uintptr_t base = (uintptr_t)d_ws;
  unsigned*  flag   = (unsigned*)base;
  int*       bsum   = (int*)(base + 4096);
  int*       cnt    = (int*)(base + 16 * 1024);
  int*       roff   = (int*)(base + 64 * 1024);
  int*       cursor = (int*)(base + 128 * 1024);
  float*     dinv   = (float*)(base + 192 * 1024);
  int*       eic    = (int*)(base + 256 * 1024);
  int*       csr    = (int*)(base + 2u * 1024 * 1024);
  ushort_t*  Ahi    = (ushort_t*)(base + 4u  * 1024 * 1024);
  ushort_t*  Alo    = (ushort_t*)(base + 10u * 1024 * 1024);
  ushort_t*  H1hi   = (ushort_t*)(base + 16u * 1024 * 1024);
  ushort_t*  H1lo   = (ushort_t*)(base + 27u * 1024 * 1024);
  float*     hw2    = (float*)(base + 38u * 1024 * 1024);
  ushort_t*  W1thi  = (ushort_t*)(base + 49u * 1024 * 1024);
  ushort_t*  W1tlo  = (ushort_t*)(base + 49u * 1024 * 1024 + 512 * 1024);
  ushort_t*  W2thi  = (ushort_t*)(base + 50u * 1024 * 1024);
  ushort_t*  W2tlo  = (ushort_t*)(base + 50u * 1024 * 1024 + 512 * 1024);

  dim3 b256(256);
  const int WCB = (C_IN * C_HID + C_HID * C_OUT + 255) / 256;  // 1024 wconv blocks

  // 1. fused setup: zero cnt | detect | weight convert
  k_setup<<<dim3(NB + 1 + WCB), b256, 0, stream>>>((const unsigned*)ei, flag, cnt,
                                                   N, NB, W1, W2,
                                                   W1thi, W1tlo, W2thi, W2tlo);
  // 2. convert + degree histogram
  k_convert<<<dim3((2 * E + 255) / 256), b256, 0, stream>>>(ei, flag, eic, cnt, E);
  // 3-4. scan
  k_scan_a<<<dim3(NB), b256, 0, stream>>>(cnt, bsum, N);
  k_scan_c<<<dim3(NB), b256, 0, stream>>>(cnt, bsum, roff, cursor, dinv, N, NB, E);
  // 5. CSR scatter
  k_scatter<<<dim3((E + 255) / 256), b256, 0, stream>>>(eic, cursor, csr, E);
  // 6. layer 1 aggregate (gather) -> bf16 split A
  k_gather4<0, 0><<<dim3(N / 4), b256, 0, stream>>>(roff, csr, dinv, x, nullptr,
                                                    Ahi, Alo, 0u, 0u);
  // 7. h1 = drop(relu(agg @ W1 + b1)) -> bf16 split   [grid 4 x 157]
  k_gemm3<1><<<dim3(C_HID / 128, (N + 63) / 64), b256, 0, stream>>>(
      Ahi, Alo, W1thi, W1tlo, b1, nullptr, H1hi, H1lo, nullptr,
      N, C_HID, C_IN, a0, a1);
  // 8. hw2' = dinv * (h1 @ W2)  (fp32, row-prescaled)  [grid 2 x 157]
  k_gemm3<0><<<dim3(C_OUT / 128, (N + 63) / 64), b256, 0, stream>>>(
      H1hi, H1lo, W2thi, W2tlo, nullptr, dinv, nullptr, nullptr, hw2,
      N, C_OUT, C_HID, 0u, 0u);
  // 9. out = drop(relu(dd * (sum hw2'[nbrs] + hw2'[self]) + b2))
  k_gather4<1, 1><<<dim3(N / 4), b256, 0, stream>>>(roff, csr, dinv, hw2, b2,
                                                    out, nullptr, b0, b1k);
}